// Round 19
// baseline (305.748 us; speedup 1.0000x reference)
//
#include <hip/hip_runtime.h>
#include <hip/hip_fp16.h>

// ---------------------------------------------------------------------------
// 2-layer GCN (PyG GCNConv): deg^{-1/2} sym norm with self-loops.
// Round 19 = round 18 + two-phase binned scatter (replaces scatter_xcd_k,
// whose WRITE_SIZE was 75MB for a 6.4MB payload: temporal write-amp).
//   - binA_k: one pass over (src,dst); LDS 128-bucket histogram (bucket =
//     dst>>10), block-range reservation (<=128 global atomics/block), dense
//     append of packed (src<<10|dst_local) -> pairs. Dense writes merge.
//   - scatB_k: 2 blocks/bucket (same XCD) drain a bucket in one burst ->
//     51KB srcs window stays L2-resident -> writes ~= payload.
//   - pairs (9.6MB) aliases thP (dead until mgemm_fused).
//   - Rest = round 18: paired-slice gathers (64B/request), fused MFMA MLP,
//     dummy-padded CSR, fdot2 accumulation.
// ---------------------------------------------------------------------------

#define NT 256
#define KE 8  // edges per thread in binA

typedef _Float16 half8 __attribute__((ext_vector_type(8)));
typedef _Float16 h2 __attribute__((ext_vector_type(2)));
typedef float floatx4 __attribute__((ext_vector_type(4)));

#if __has_builtin(__builtin_amdgcn_fdot2)
__device__ __forceinline__ float dot2f(h2 a, h2 b, float c) {
    return __builtin_amdgcn_fdot2(a, b, c, false);
}
#else
__device__ __forceinline__ float dot2f(h2 a, h2 b, float c) {
    return c + (float)a.x * (float)b.x + (float)a.y * (float)b.y;
}
#endif

// ---------------- CSR build ----------------

__global__ void zero_cnt_k(int* __restrict__ cnt, int n) {
    int i = blockIdx.x * NT + threadIdx.x;
    if (i < n) cnt[i] = 0;
}

__global__ void deg_count_k(const int* __restrict__ dst, int* __restrict__ c, int e) {
    int i = blockIdx.x * NT + threadIdx.x;
    if (i < e) atomicAdd(&c[dst[i]], 1);
}

// exclusive scan of PADDED counts -> rowptr; emits dinv, pdeg
__global__ void scan1_k(const int* __restrict__ counts, int* __restrict__ rowptr,
                        int* __restrict__ bsum, float* __restrict__ dinv,
                        int* __restrict__ pdeg, int n) {
    __shared__ int s[NT];
    int tid = threadIdx.x, i = blockIdx.x * NT + tid;
    int v = (i < n) ? counts[i] : 0;
    int pv = (v + 7) & ~7;
    if (i < n) {
        dinv[i] = rsqrtf((float)(v + 1));  // +1 self-loop
        pdeg[i] = pv;
    }
    s[tid] = pv;
    __syncthreads();
    for (int off = 1; off < NT; off <<= 1) {
        int t = (tid >= off) ? s[tid - off] : 0;
        __syncthreads();
        if (tid >= off) s[tid] += t;
        __syncthreads();
    }
    if (i < n) rowptr[i] = s[tid] - pv;
    if (tid == NT - 1) bsum[blockIdx.x] = s[tid];
}

__global__ void scan2_k(int* __restrict__ bsum, int nb) {
    __shared__ int s[512];
    __shared__ int carry;
    int tid = threadIdx.x;
    if (tid == 0) carry = 0;
    __syncthreads();
    for (int base = 0; base < nb; base += 512) {
        int i = base + tid;
        int v = (i < nb) ? bsum[i] : 0;
        s[tid] = v;
        __syncthreads();
        for (int off = 1; off < 512; off <<= 1) {
            int t = (tid >= off) ? s[tid - off] : 0;
            __syncthreads();
            if (tid >= off) s[tid] += t;
            __syncthreads();
        }
        int tot = s[511];
        if (i < nb) bsum[i] = s[tid] - v + carry;
        __syncthreads();
        if (tid == 0) carry += tot;
        __syncthreads();
    }
}

__global__ void scan3_k(int* __restrict__ rowptr, const int* __restrict__ bsum,
                        int* __restrict__ cursor, int n) {
    int i = blockIdx.x * NT + threadIdx.x;
    if (i < n) {
        int r = rowptr[i] + bsum[i / NT];
        rowptr[i] = r;
        cursor[i] = r;
    }
}

// bucket cursors/starts from padded rowptr (bucket = node>>10, 128 buckets)
__global__ void bktinit_k(const int* __restrict__ rowptr, int* __restrict__ bktcur,
                          int* __restrict__ bktstart, int n) {
    int t = threadIdx.x;  // 128 threads
    int v = ((t << 10) < n) ? rowptr[t << 10] : 0;
    bktcur[t] = v;
    bktstart[t] = v;
}

// ---- phase A: bin edges into per-bucket dense pair regions ----
// pair word = (src << 10) | (dst & 1023); bucket = dst >> 10.
__global__ __launch_bounds__(NT) void binA_k(
    const int* __restrict__ src, const int* __restrict__ dst,
    int* __restrict__ bktcur, unsigned* __restrict__ pairs, int e) {
    __shared__ int lh[128];
    __shared__ int lbase[128];
    int tid = threadIdx.x;
    if (tid < 128) lh[tid] = 0;
    __syncthreads();
    int base = blockIdx.x * (NT * KE);
    int sv[KE];
    unsigned meta[KE];
#pragma unroll
    for (int k = 0; k < KE; ++k) {
        int ei = base + k * NT + tid;
        if (ei < e) {
            int d = dst[ei];
            sv[k] = src[ei];
            int b = d >> 10;
            int lr = atomicAdd(&lh[b], 1);  // LDS atomic
            meta[k] = ((unsigned)b << 22) | ((unsigned)lr << 10) | (unsigned)(d & 1023);
        } else {
            sv[k] = 0;
            meta[k] = 0xffffffffu;
        }
    }
    __syncthreads();
    if (tid < 128 && lh[tid] > 0)
        lbase[tid] = atomicAdd(&bktcur[tid], lh[tid]);  // <=128 global/block
    __syncthreads();
#pragma unroll
    for (int k = 0; k < KE; ++k) {
        if (meta[k] != 0xffffffffu) {
            int b = (int)(meta[k] >> 22);
            int lr = (int)((meta[k] >> 10) & 0xfffu);
            pairs[lbase[b] + lr] = ((unsigned)sv[k] << 10) | (meta[k] & 1023u);
        }
    }
}

// ---- phase B: per-bucket scatter to final CSR positions ----
// 2 blocks per bucket (blockIdx and blockIdx+128: same XCD via %8 dispatch);
// bucket window (~51KB of srcs) stays L2-resident during the burst.
__global__ __launch_bounds__(NT) void scatB_k(
    const unsigned* __restrict__ pairs, const int* __restrict__ bktstart,
    const int* __restrict__ bktcur, int* __restrict__ cursor,
    int* __restrict__ srcs) {
    int i = blockIdx.x;                         // 0..255
    int b = (i & 7) * 16 + ((i >> 3) & 15);     // bucket 0..127
    int sub = i >> 7;                           // 0/1
    int start = bktstart[b];
    int cnt = bktcur[b] - start;
    if (cnt <= 0) return;
    int nbase = b << 10;
    int half = (cnt + 1) >> 1;
    int lo = start + sub * half;
    int hi = start + ((sub == 0) ? half : cnt);
    for (int j = lo + (int)threadIdx.x; j < hi; j += NT) {
        unsigned p = pairs[j];
        int d = nbase + (int)(p & 1023u);
        int pos = atomicAdd(&cursor[d], 1);
        srcs[pos] = (int)(p >> 10);
    }
}

// precise pad fill: fill [cursor[i], rowptr[i]+pdeg[i]) with dummy N;
// last node adds +8 slack for the unconditional one-batch-ahead prefetch.
__global__ void fill_pads_k(const int* __restrict__ cursor,
                            const int* __restrict__ rowptr,
                            const int* __restrict__ pdeg,
                            int* __restrict__ srcs, int n) {
    int i = blockIdx.x * NT + threadIdx.x;
    if (i >= n) return;
    int e  = cursor[i];
    int e1 = rowptr[i] + pdeg[i];
    for (; e < e1; ++e) srcs[e] = n;
    if (i == n - 1) {
#pragma unroll
        for (int j = 0; j < 8; ++j) srcs[e1 + j] = n;
    }
}

// ---------------- conv1T: x -> xhP[4][N+1][32] fp16 (row N zeroed) ---------
__global__ void conv1T_k(const float* __restrict__ x, const float* __restrict__ dinv,
                         __half* __restrict__ xhP, int n) {
    int t = blockIdx.x * NT + threadIdx.x;
    int node = t >> 3;
    if (node > n) return;
    int q = t & 7;
    int4 o0, o1;
    if (node == n) {
        o0 = make_int4(0, 0, 0, 0);
        o1 = o0;
    } else {
        float dn = dinv[node];
        const float4* xp =
            reinterpret_cast<const float4*>(x + (size_t)node * 128 + q * 16);
        __half2 h[8];
#pragma unroll
        for (int j = 0; j < 4; ++j) {
            float4 a = xp[j];
            h[2 * j + 0] = __floats2half2_rn(a.x * dn, a.y * dn);
            h[2 * j + 1] = __floats2half2_rn(a.z * dn, a.w * dn);
        }
        o0 = reinterpret_cast<int4*>(h)[0];
        o1 = reinterpret_cast<int4*>(h)[1];
    }
    int4* op = reinterpret_cast<int4*>(
        xhP + ((size_t)(q >> 1) * (n + 1) + node) * 32 + (q & 1) * 16);
    op[0] = o0;
    op[1] = o1;
}

// ---------------- paired gathers: groups of 16 lanes, 64B/edge requests ----

__global__ __launch_bounds__(NT) void gatherT128_k(
    const int* __restrict__ rowptr, const int* __restrict__ pdeg,
    const int* __restrict__ srcs, const float* __restrict__ dinv,
    const __half* __restrict__ xhP, __half2* __restrict__ aggT, int n) {
    const int q8    = blockIdx.x & 7;   // (pair, node-16-block parity)
    const int pair  = q8 & 3;
    const int chunk = blockIdx.x >> 3;
    const int lane  = threadIdx.x & 63;
    const int wid   = threadIdx.x >> 6;
    const int g     = lane >> 4;   // node sub-group 0..3
    const int c     = lane & 15;   // half2 col within 32-col pair
    const int node  = chunk * 32 + (q8 >> 2) * 16 + wid * 4 + g;
    if (node >= n) return;  // uniform within each 16-lane group

    const int e0 = rowptr[node];
    const int pd = pdeg[node];
    const char* base = (const char*)(xhP + (size_t)pair * (n + 1) * 32);
    const unsigned c4 = (unsigned)c * 4u;
    const h2 b10 = {(_Float16)1.0f, (_Float16)0.0f};
    const h2 b01 = {(_Float16)0.0f, (_Float16)1.0f};

    // self-loop (64 B row)
    h2 fs = *(const h2*)(base + (size_t)node * 64 + c4);
    float ax = dot2f(fs, b10, 0.0f);
    float ay = dot2f(fs, b01, 0.0f);

    int sidx = srcs[e0 + (c & 7)];
    for (int jb = 0; jb < pd; jb += 8) {
        int snext = srcs[e0 + jb + 8 + (c & 7)];  // padded buffer
#pragma unroll
        for (int u = 0; u < 8; ++u) {
            int s = __shfl(sidx, (lane & 0x30) | u, 64);
            h2 f = *(const h2*)(base + (unsigned)s * 64u + c4);
            ax = dot2f(f, b10, ax);
            ay = dot2f(f, b01, ay);
        }
        sidx = snext;
    }

    float dn = dinv[node];
    int sl = pair * 2 + (c >> 3);  // aggT stays [8][N][16]
    aggT[((size_t)sl * n + node) * 8 + (c & 7)] =
        __floats2half2_rn(ax * dn, ay * dn);
}

// gatherT64: thP[2][N+1][32]; writes row-major fp32 out (+b2), 128B/group.
__global__ __launch_bounds__(NT) void gatherT64_k(
    const int* __restrict__ rowptr, const int* __restrict__ pdeg,
    const int* __restrict__ srcs, const float* __restrict__ dinv,
    const __half* __restrict__ thP, const float* __restrict__ b2,
    float* __restrict__ out, int n) {
    const int q8    = blockIdx.x & 7;
    const int pair  = q8 & 1;
    const int chunk = blockIdx.x >> 3;
    const int lane  = threadIdx.x & 63;
    const int wid   = threadIdx.x >> 6;
    const int g     = lane >> 4;
    const int c     = lane & 15;
    const int node  = chunk * 64 + (q8 >> 1) * 16 + wid * 4 + g;
    if (node >= n) return;

    const int e0 = rowptr[node];
    const int pd = pdeg[node];
    const char* base = (const char*)(thP + (size_t)pair * (n + 1) * 32);
    const unsigned c4 = (unsigned)c * 4u;
    const h2 b10 = {(_Float16)1.0f, (_Float16)0.0f};
    const h2 b01 = {(_Float16)0.0f, (_Float16)1.0f};

    h2 fs = *(const h2*)(base + (size_t)node * 64 + c4);
    float ax = dot2f(fs, b10, 0.0f);
    float ay = dot2f(fs, b01, 0.0f);

    int sidx = srcs[e0 + (c & 7)];
    for (int jb = 0; jb < pd; jb += 8) {
        int snext = srcs[e0 + jb + 8 + (c & 7)];
#pragma unroll
        for (int u = 0; u < 8; ++u) {
            int s = __shfl(sidx, (lane & 0x30) | u, 64);
            h2 f = *(const h2*)(base + (unsigned)s * 64u + c4);
            ax = dot2f(f, b10, ax);
            ay = dot2f(f, b01, ay);
        }
        sidx = snext;
    }

    float dn = dinv[node];
    int col = pair * 32 + c * 2;
    *reinterpret_cast<float2*>(&out[(size_t)node * 64 + col]) =
        make_float2(ax * dn + b2[col], ay * dn + b2[col + 1]);
}

// ---------------- fused MLP: thP = (relu(aggT@W1 + b1) @ W2) * dinv --------
__global__ __launch_bounds__(NT) void mgemm_fused_k(
    const __half* __restrict__ aggT, const float* __restrict__ W1,
    const float* __restrict__ b1, const float* __restrict__ W2,
    const float* __restrict__ dinv, __half* __restrict__ thP, int n) {
    __shared__ _Float16 h1s[64][136];

    const int wid  = threadIdx.x >> 6;
    const int lane = threadIdx.x & 63;
    const int lrow = lane & 15;
    const int kgrp = lane >> 4;

    if (blockIdx.x == 0 && threadIdx.x < 64) {
        int pr = threadIdx.x >> 5, j = threadIdx.x & 31;
        thP[((size_t)pr * (n + 1) + n) * 32 + j] = __float2half(0.0f);
    }

    half8 bf1[2][4];
    float bv[2];
#pragma unroll
    for (int nt = 0; nt < 2; ++nt) {
        int col = wid * 32 + nt * 16 + lrow;
#pragma unroll
        for (int kk = 0; kk < 4; ++kk)
#pragma unroll
            for (int j = 0; j < 8; ++j)
                bf1[nt][kk][j] = (_Float16)W1[(size_t)(kk * 32 + kgrp * 8 + j) * 128 + col];
        bv[nt] = b1[col];
    }
    half8 bf2[4];
    {
        int col = wid * 16 + lrow;
#pragma unroll
        for (int kk = 0; kk < 4; ++kk)
#pragma unroll
            for (int j = 0; j < 8; ++j)
                bf2[kk][j] = (_Float16)W2[(size_t)(kk * 32 + kgrp * 8 + j) * 64 + col];
    }

    const int m0 = blockIdx.x * 64;

    floatx4 acc1[4][2];
#pragma unroll
    for (int mt = 0; mt < 4; ++mt)
#pragma unroll
        for (int nt = 0; nt < 2; ++nt) acc1[mt][nt] = floatx4{0.f, 0.f, 0.f, 0.f};

#pragma unroll
    for (int kk = 0; kk < 4; ++kk) {
        const int k0 = kk * 32 + kgrp * 8;
        half8 af[4];
#pragma unroll
        for (int mt = 0; mt < 4; ++mt) {
            int row = m0 + mt * 16 + lrow;
            if (row >= n) row = n - 1;  // clamp; final stores guarded
            af[mt] = *reinterpret_cast<const half8*>(
                &aggT[(((size_t)(k0 >> 4)) * n + row) * 16 + (k0 & 15)]);
        }
#pragma unroll
        for (int mt = 0; mt < 4; ++mt)
#pragma unroll
            for (int nt = 0; nt < 2; ++nt)
                acc1[mt][nt] = __builtin_amdgcn_mfma_f32_16x16x32_f16(
                    af[mt], bf1[nt][kk], acc1[mt][nt], 0, 0, 0);
    }

#pragma unroll
    for (int mt = 0; mt < 4; ++mt) {
#pragma unroll
        for (int r = 0; r < 4; ++r) {
            int rloc = mt * 16 + kgrp * 4 + r;
#pragma unroll
            for (int nt = 0; nt < 2; ++nt) {
                float v = fmaxf(acc1[mt][nt][r] + bv[nt], 0.0f);
                h1s[rloc][wid * 32 + nt * 16 + lrow] = (_Float16)v;
            }
        }
    }
    __syncthreads();

    floatx4 acc2[4];
#pragma unroll
    for (int mt = 0; mt < 4; ++mt) acc2[mt] = floatx4{0.f, 0.f, 0.f, 0.f};

#pragma unroll
    for (int kk = 0; kk < 4; ++kk) {
        const int k0 = kk * 32 + kgrp * 8;
#pragma unroll
        for (int mt = 0; mt < 4; ++mt) {
            half8 af = *reinterpret_cast<const half8*>(&h1s[mt * 16 + lrow][k0]);
            acc2[mt] = __builtin_amdgcn_mfma_f32_16x16x32_f16(
                af, bf2[kk], acc2[mt], 0, 0, 0);
        }
    }

#pragma unroll
    for (int mt = 0; mt < 4; ++mt) {
#pragma unroll
        for (int r = 0; r < 4; ++r) {
            int row = m0 + mt * 16 + kgrp * 4 + r;
            if (row < n) {
                float v = acc2[mt][r] * dinv[row];
                int col = wid * 16 + lrow;
                thP[((size_t)(col >> 5) * (n + 1) + row) * 32 + (col & 31)] =
                    __float2half(v);
            }
        }
    }
}

// ---------------------------------------------------------------------------

extern "C" void kernel_launch(void* const* d_in, const int* in_sizes, int n_in,
                              void* d_out, int out_size, void* d_ws, size_t ws_size,
                              hipStream_t stream) {
    const float* x   = (const float*)d_in[0];
    const int*   ei  = (const int*)d_in[1];
    const float* W1  = (const float*)d_in[2];
    const float* b1  = (const float*)d_in[3];
    const float* W2  = (const float*)d_in[4];
    const float* b2  = (const float*)d_in[5];
    float*       out = (float*)d_out;

    const int N = in_sizes[0] / 128;
    const int E = in_sizes[1] / 2;
    const int* srcp = ei;      // edge_index[0]
    const int* dstp = ei + E;  // edge_index[1]

    const int nb   = (N + NT - 1) / NT;
    const int EPAD = E + 8 * N + 64;  // >= sum(padded degrees) + tail slack

    // workspace (512B-aligned):
    //   dinv[N] | cnt[N] | pdeg[N] | rowptr[N] | bsum[nb] | bktcur[128] |
    //   bktstart[128] | srcs[EPAD]
    //   | xhP[4][N+1][32] fp16 | aggT[8][N][16] fp16
    //   | thP[2][N+1][32] fp16  (pairs[EPAD] u32 aliases thP: 9.6 < 12.8 MB)
    char* ws = (char*)d_ws;
    size_t off = 0;
    auto alloc = [&](size_t bytes) {
        char* p = ws + off;
        off = (off + bytes + 511) & ~(size_t)511;
        return p;
    };
    float*  dinv     = (float*)alloc((size_t)N * 4);
    int*    cnt      = (int*)alloc((size_t)N * 4);  // counts, then CSR cursor
    int*    pdeg     = (int*)alloc((size_t)N * 4);
    int*    rowptr   = (int*)alloc((size_t)N * 4);
    int*    bsum     = (int*)alloc((size_t)nb * 4);
    int*    bktcur   = (int*)alloc(128 * 4);
    int*    bktstart = (int*)alloc(128 * 4);
    int*    srcs     = (int*)alloc((size_t)EPAD * 4);
    __half* xhP      = (__half*)alloc((size_t)(N + 1) * 128 * 2);
    __half* aggT     = (__half*)alloc((size_t)N * 128 * 2);
    __half* thP      = (__half*)alloc((size_t)(N + 1) * 64 * 2);
    unsigned* pairs  = (unsigned*)thP;  // alias: dead until mgemm_fused

    // ---- padded CSR build + norm ----
    zero_cnt_k<<<nb, NT, 0, stream>>>(cnt, N);
    deg_count_k<<<(E + NT - 1) / NT, NT, 0, stream>>>(dstp, cnt, E);
    scan1_k<<<nb, NT, 0, stream>>>(cnt, rowptr, bsum, dinv, pdeg, N);
    scan2_k<<<1, 512, 0, stream>>>(bsum, nb);
    scan3_k<<<nb, NT, 0, stream>>>(rowptr, bsum, cnt, N);

    // ---- two-phase binned scatter ----
    bktinit_k<<<1, 128, 0, stream>>>(rowptr, bktcur, bktstart, N);
    binA_k<<<(E + NT * KE - 1) / (NT * KE), NT, 0, stream>>>(
        srcp, dstp, bktcur, pairs, E);
    scatB_k<<<256, NT, 0, stream>>>(pairs, bktstart, bktcur, cnt, srcs);
    fill_pads_k<<<nb, NT, 0, stream>>>(cnt, rowptr, pdeg, srcs, N);

    // ---- layer 1: xhP (dummy row zeroed) -> aggT ----
    conv1T_k<<<((N + 1) * 8 + NT - 1) / NT, NT, 0, stream>>>(x, dinv, xhP, N);
    gatherT128_k<<<((N + 31) / 32) * 8, NT, 0, stream>>>(
        rowptr, pdeg, srcs, dinv, xhP, (__half2*)aggT, N);

    // ---- fused MLP: aggT -> thP = (relu(aggT@W1+b1)@W2)*dinv ----
    mgemm_fused_k<<<(N + 63) / 64, NT, 0, stream>>>(
        aggT, W1, b1, W2, dinv, thP, N);

    // ---- layer 2 gather -> out (+b2) ----
    gatherT64_k<<<((N + 63) / 64) * 8, NT, 0, stream>>>(
        rowptr, pdeg, srcs, dinv, thP, b2, out, N);
}

// Round 20
// 200.610 us; speedup vs baseline: 1.5241x; 1.5241x over previous
//
#include <hip/hip_runtime.h>
#include <hip/hip_fp16.h>

// ---------------------------------------------------------------------------
// 2-layer GCN (PyG GCNConv): deg^{-1/2} sym norm with self-loops.
// Round 20 = round 19 with the CSR build collapsed to 2 kernels.
//   - Fixed-stride bucket regions (CAP pairs, SCAP srcs slots per bucket of
//     1024 nodes). binA bins (src,dst)->pairs with count-relative cursors
//     (bktcur memsetAsync'd to 0). scatB (1 block x 1024 thr per bucket,
//     XCD-local region): LDS per-dst count -> dinv/pdeg -> LDS scan ->
//     absolute rowptr -> placement pass -> pad fill. Replaces deg_count +
//     scan1/2/3 + bktinit + scatter + fill_pads (9 dispatches -> 2).
//   - Rest = round 19: paired-slice gathers (64B/request), fused MFMA MLP,
//     dummy-padded CSR (dummy index N -> zeroed payload row), fdot2 accum.
// ---------------------------------------------------------------------------

#define NT 256
#define KE 8            // edges per thread in binA
#define CAP 20480       // pairs capacity per bucket (actual ~12.5k)
#define SCAP 28928      // srcs slots per bucket (>= CAP + 7*1024 + 8)

typedef _Float16 half8 __attribute__((ext_vector_type(8)));
typedef _Float16 h2 __attribute__((ext_vector_type(2)));
typedef float floatx4 __attribute__((ext_vector_type(4)));

#if __has_builtin(__builtin_amdgcn_fdot2)
__device__ __forceinline__ float dot2f(h2 a, h2 b, float c) {
    return __builtin_amdgcn_fdot2(a, b, c, false);
}
#else
__device__ __forceinline__ float dot2f(h2 a, h2 b, float c) {
    return c + (float)a.x * (float)b.x + (float)a.y * (float)b.y;
}
#endif

// ---- phase A: bin edges into fixed-stride bucket regions ----
// pair word = (src << 10) | (dst & 1023); bucket = dst >> 10.
// bktcur[128] holds COUNT-relative cursors (pre-zeroed via memsetAsync).
__global__ __launch_bounds__(NT) void binA_k(
    const int* __restrict__ src, const int* __restrict__ dst,
    int* __restrict__ bktcur, unsigned* __restrict__ pairs, int e) {
    __shared__ int lh[128];
    __shared__ int lbase[128];
    int tid = threadIdx.x;
    if (tid < 128) lh[tid] = 0;
    __syncthreads();
    int base = blockIdx.x * (NT * KE);
    int sv[KE];
    unsigned meta[KE];
#pragma unroll
    for (int k = 0; k < KE; ++k) {
        int ei = base + k * NT + tid;
        if (ei < e) {
            int d = dst[ei];
            sv[k] = src[ei];
            int b = d >> 10;
            int lr = atomicAdd(&lh[b], 1);  // LDS atomic
            meta[k] = ((unsigned)b << 22) | ((unsigned)lr << 10) | (unsigned)(d & 1023);
        } else {
            sv[k] = 0;
            meta[k] = 0xffffffffu;
        }
    }
    __syncthreads();
    if (tid < 128 && lh[tid] > 0)
        lbase[tid] = atomicAdd(&bktcur[tid], lh[tid]);  // <=128 global/block
    __syncthreads();
#pragma unroll
    for (int k = 0; k < KE; ++k) {
        if (meta[k] != 0xffffffffu) {
            int b = (int)(meta[k] >> 22);
            int lr = (int)((meta[k] >> 10) & 0xfffu);
            pairs[(size_t)b * CAP + lbase[b] + lr] =
                ((unsigned)sv[k] << 10) | (meta[k] & 1023u);
        }
    }
}

// ---- phase B: per-bucket CSR build + scatter (1 block = 1 bucket) ----
// 1024 threads. Emits dinv, pdeg, rowptr (absolute, bucket-strided srcs),
// places srcs, fills pads (+8 tail slack for the gather prefetch).
__global__ __launch_bounds__(1024) void scatB_k(
    const unsigned* __restrict__ pairs, const int* __restrict__ bktcur,
    int* __restrict__ rowptr, int* __restrict__ pdeg, float* __restrict__ dinv,
    int* __restrict__ srcs, int n) {
    __shared__ int lc[1024];
    __shared__ int sa[1024];
    const int i = blockIdx.x;                     // 0..127
    const int b = (i & 7) * 16 + (i >> 3);        // bucket, XCD-local regions
    const int tid = threadIdx.x;
    const int nbase = b << 10;
    if (nbase >= n) return;
    const int cntb = bktcur[b];
    const size_t pbase = (size_t)b * CAP;
    const size_t sbase = (size_t)b * SCAP;

    lc[tid] = 0;
    __syncthreads();
    for (int j = tid; j < cntb; j += 1024)
        atomicAdd(&lc[pairs[pbase + j] & 1023u], 1);
    __syncthreads();

    const int c  = lc[tid];
    const int pv = (c + 7) & ~7;
    // inclusive scan of pv over 1024 threads (in-place, 2 syncs/step)
    sa[tid] = pv;
    __syncthreads();
    for (int off = 1; off < 1024; off <<= 1) {
        int t = (tid >= off) ? sa[tid - off] : 0;
        __syncthreads();
        if (tid >= off) sa[tid] += t;
        __syncthreads();
    }
    const int oex = sa[tid] - pv;  // exclusive offset within bucket
    const int total = sa[1023];

    const int d = nbase + tid;
    if (d < n) {
        rowptr[d] = (int)sbase + oex;
        pdeg[d]   = pv;
        dinv[d]   = rsqrtf((float)(c + 1));  // +1 self-loop
    }
    lc[tid] = oex;  // per-dst placement cursor
    __syncthreads();

    for (int j = tid; j < cntb; j += 1024) {
        unsigned p = pairs[pbase + j];
        int dl = (int)(p & 1023u);
        int pos = atomicAdd(&lc[dl], 1);
        srcs[sbase + pos] = (int)(p >> 10);
    }
    __syncthreads();

    // pads: [oex+c, oex+pv) per dst; +8 tail slack after bucket total
    for (int k = oex + c; k < oex + pv; ++k) srcs[sbase + k] = n;
    if (tid < 8) srcs[sbase + total + tid] = n;
}

// ---------------- conv1T: x -> xhP[4][N+1][32] fp16 (row N zeroed) ---------
__global__ void conv1T_k(const float* __restrict__ x, const float* __restrict__ dinv,
                         __half* __restrict__ xhP, int n) {
    int t = blockIdx.x * NT + threadIdx.x;
    int node = t >> 3;
    if (node > n) return;
    int q = t & 7;
    int4 o0, o1;
    if (node == n) {
        o0 = make_int4(0, 0, 0, 0);
        o1 = o0;
    } else {
        float dn = dinv[node];
        const float4* xp =
            reinterpret_cast<const float4*>(x + (size_t)node * 128 + q * 16);
        __half2 h[8];
#pragma unroll
        for (int j = 0; j < 4; ++j) {
            float4 a = xp[j];
            h[2 * j + 0] = __floats2half2_rn(a.x * dn, a.y * dn);
            h[2 * j + 1] = __floats2half2_rn(a.z * dn, a.w * dn);
        }
        o0 = reinterpret_cast<int4*>(h)[0];
        o1 = reinterpret_cast<int4*>(h)[1];
    }
    int4* op = reinterpret_cast<int4*>(
        xhP + ((size_t)(q >> 1) * (n + 1) + node) * 32 + (q & 1) * 16);
    op[0] = o0;
    op[1] = o1;
}

// ---------------- paired gathers: groups of 16 lanes, 64B/edge requests ----

__global__ __launch_bounds__(NT) void gatherT128_k(
    const int* __restrict__ rowptr, const int* __restrict__ pdeg,
    const int* __restrict__ srcs, const float* __restrict__ dinv,
    const __half* __restrict__ xhP, __half2* __restrict__ aggT, int n) {
    const int q8    = blockIdx.x & 7;   // (pair, node-16-block parity)
    const int pair  = q8 & 3;
    const int chunk = blockIdx.x >> 3;
    const int lane  = threadIdx.x & 63;
    const int wid   = threadIdx.x >> 6;
    const int g     = lane >> 4;   // node sub-group 0..3
    const int c     = lane & 15;   // half2 col within 32-col pair
    const int node  = chunk * 32 + (q8 >> 2) * 16 + wid * 4 + g;
    if (node >= n) return;  // uniform within each 16-lane group

    const int e0 = rowptr[node];
    const int pd = pdeg[node];
    const char* base = (const char*)(xhP + (size_t)pair * (n + 1) * 32);
    const unsigned c4 = (unsigned)c * 4u;
    const h2 b10 = {(_Float16)1.0f, (_Float16)0.0f};
    const h2 b01 = {(_Float16)0.0f, (_Float16)1.0f};

    // self-loop (64 B row)
    h2 fs = *(const h2*)(base + (size_t)node * 64 + c4);
    float ax = dot2f(fs, b10, 0.0f);
    float ay = dot2f(fs, b01, 0.0f);

    int sidx = srcs[e0 + (c & 7)];
    for (int jb = 0; jb < pd; jb += 8) {
        int snext = srcs[e0 + jb + 8 + (c & 7)];  // padded buffer
#pragma unroll
        for (int u = 0; u < 8; ++u) {
            int s = __shfl(sidx, (lane & 0x30) | u, 64);
            h2 f = *(const h2*)(base + (unsigned)s * 64u + c4);
            ax = dot2f(f, b10, ax);
            ay = dot2f(f, b01, ay);
        }
        sidx = snext;
    }

    float dn = dinv[node];
    int sl = pair * 2 + (c >> 3);  // aggT stays [8][N][16]
    aggT[((size_t)sl * n + node) * 8 + (c & 7)] =
        __floats2half2_rn(ax * dn, ay * dn);
}

// gatherT64: thP[2][N+1][32]; writes row-major fp32 out (+b2), 128B/group.
__global__ __launch_bounds__(NT) void gatherT64_k(
    const int* __restrict__ rowptr, const int* __restrict__ pdeg,
    const int* __restrict__ srcs, const float* __restrict__ dinv,
    const __half* __restrict__ thP, const float* __restrict__ b2,
    float* __restrict__ out, int n) {
    const int q8    = blockIdx.x & 7;
    const int pair  = q8 & 1;
    const int chunk = blockIdx.x >> 3;
    const int lane  = threadIdx.x & 63;
    const int wid   = threadIdx.x >> 6;
    const int g     = lane >> 4;
    const int c     = lane & 15;
    const int node  = chunk * 64 + (q8 >> 1) * 16 + wid * 4 + g;
    if (node >= n) return;

    const int e0 = rowptr[node];
    const int pd = pdeg[node];
    const char* base = (const char*)(thP + (size_t)pair * (n + 1) * 32);
    const unsigned c4 = (unsigned)c * 4u;
    const h2 b10 = {(_Float16)1.0f, (_Float16)0.0f};
    const h2 b01 = {(_Float16)0.0f, (_Float16)1.0f};

    h2 fs = *(const h2*)(base + (size_t)node * 64 + c4);
    float ax = dot2f(fs, b10, 0.0f);
    float ay = dot2f(fs, b01, 0.0f);

    int sidx = srcs[e0 + (c & 7)];
    for (int jb = 0; jb < pd; jb += 8) {
        int snext = srcs[e0 + jb + 8 + (c & 7)];
#pragma unroll
        for (int u = 0; u < 8; ++u) {
            int s = __shfl(sidx, (lane & 0x30) | u, 64);
            h2 f = *(const h2*)(base + (unsigned)s * 64u + c4);
            ax = dot2f(f, b10, ax);
            ay = dot2f(f, b01, ay);
        }
        sidx = snext;
    }

    float dn = dinv[node];
    int col = pair * 32 + c * 2;
    *reinterpret_cast<float2*>(&out[(size_t)node * 64 + col]) =
        make_float2(ax * dn + b2[col], ay * dn + b2[col + 1]);
}

// ---------------- fused MLP: thP = (relu(aggT@W1 + b1) @ W2) * dinv --------
__global__ __launch_bounds__(NT) void mgemm_fused_k(
    const __half* __restrict__ aggT, const float* __restrict__ W1,
    const float* __restrict__ b1, const float* __restrict__ W2,
    const float* __restrict__ dinv, __half* __restrict__ thP, int n) {
    __shared__ _Float16 h1s[64][136];

    const int wid  = threadIdx.x >> 6;
    const int lane = threadIdx.x & 63;
    const int lrow = lane & 15;
    const int kgrp = lane >> 4;

    if (blockIdx.x == 0 && threadIdx.x < 64) {
        int pr = threadIdx.x >> 5, j = threadIdx.x & 31;
        thP[((size_t)pr * (n + 1) + n) * 32 + j] = __float2half(0.0f);
    }

    half8 bf1[2][4];
    float bv[2];
#pragma unroll
    for (int nt = 0; nt < 2; ++nt) {
        int col = wid * 32 + nt * 16 + lrow;
#pragma unroll
        for (int kk = 0; kk < 4; ++kk)
#pragma unroll
            for (int j = 0; j < 8; ++j)
                bf1[nt][kk][j] = (_Float16)W1[(size_t)(kk * 32 + kgrp * 8 + j) * 128 + col];
        bv[nt] = b1[col];
    }
    half8 bf2[4];
    {
        int col = wid * 16 + lrow;
#pragma unroll
        for (int kk = 0; kk < 4; ++kk)
#pragma unroll
            for (int j = 0; j < 8; ++j)
                bf2[kk][j] = (_Float16)W2[(size_t)(kk * 32 + kgrp * 8 + j) * 64 + col];
    }

    const int m0 = blockIdx.x * 64;

    floatx4 acc1[4][2];
#pragma unroll
    for (int mt = 0; mt < 4; ++mt)
#pragma unroll
        for (int nt = 0; nt < 2; ++nt) acc1[mt][nt] = floatx4{0.f, 0.f, 0.f, 0.f};

#pragma unroll
    for (int kk = 0; kk < 4; ++kk) {
        const int k0 = kk * 32 + kgrp * 8;
        half8 af[4];
#pragma unroll
        for (int mt = 0; mt < 4; ++mt) {
            int row = m0 + mt * 16 + lrow;
            if (row >= n) row = n - 1;  // clamp; final stores guarded
            af[mt] = *reinterpret_cast<const half8*>(
                &aggT[(((size_t)(k0 >> 4)) * n + row) * 16 + (k0 & 15)]);
        }
#pragma unroll
        for (int mt = 0; mt < 4; ++mt)
#pragma unroll
            for (int nt = 0; nt < 2; ++nt)
                acc1[mt][nt] = __builtin_amdgcn_mfma_f32_16x16x32_f16(
                    af[mt], bf1[nt][kk], acc1[mt][nt], 0, 0, 0);
    }

#pragma unroll
    for (int mt = 0; mt < 4; ++mt) {
#pragma unroll
        for (int r = 0; r < 4; ++r) {
            int rloc = mt * 16 + kgrp * 4 + r;
#pragma unroll
            for (int nt = 0; nt < 2; ++nt) {
                float v = fmaxf(acc1[mt][nt][r] + bv[nt], 0.0f);
                h1s[rloc][wid * 32 + nt * 16 + lrow] = (_Float16)v;
            }
        }
    }
    __syncthreads();

    floatx4 acc2[4];
#pragma unroll
    for (int mt = 0; mt < 4; ++mt) acc2[mt] = floatx4{0.f, 0.f, 0.f, 0.f};

#pragma unroll
    for (int kk = 0; kk < 4; ++kk) {
        const int k0 = kk * 32 + kgrp * 8;
#pragma unroll
        for (int mt = 0; mt < 4; ++mt) {
            half8 af = *reinterpret_cast<const half8*>(&h1s[mt * 16 + lrow][k0]);
            acc2[mt] = __builtin_amdgcn_mfma_f32_16x16x32_f16(
                af, bf2[kk], acc2[mt], 0, 0, 0);
        }
    }

#pragma unroll
    for (int mt = 0; mt < 4; ++mt) {
#pragma unroll
        for (int r = 0; r < 4; ++r) {
            int row = m0 + mt * 16 + kgrp * 4 + r;
            if (row < n) {
                float v = acc2[mt][r] * dinv[row];
                int col = wid * 16 + lrow;
                thP[((size_t)(col >> 5) * (n + 1) + row) * 32 + (col & 31)] =
                    __float2half(v);
            }
        }
    }
}

// ---------------------------------------------------------------------------

extern "C" void kernel_launch(void* const* d_in, const int* in_sizes, int n_in,
                              void* d_out, int out_size, void* d_ws, size_t ws_size,
                              hipStream_t stream) {
    const float* x   = (const float*)d_in[0];
    const int*   ei  = (const int*)d_in[1];
    const float* W1  = (const float*)d_in[2];
    const float* b1  = (const float*)d_in[3];
    const float* W2  = (const float*)d_in[4];
    const float* b2  = (const float*)d_in[5];
    float*       out = (float*)d_out;

    const int N = in_sizes[0] / 128;
    const int E = in_sizes[1] / 2;
    const int* srcp = ei;      // edge_index[0]
    const int* dstp = ei + E;  // edge_index[1]

    // workspace (512B-aligned):
    //   dinv[N] | pdeg[N] | rowptr[N] | bktcur[128] | srcs[128*SCAP]
    //   | xhP[4][N+1][32] fp16 | aggT[8][N][16] fp16
    //   | thP[2][N+1][32] fp16  (pairs[128*CAP] u32 aliases thP: 10.5<12.8MB)
    char* ws = (char*)d_ws;
    size_t off = 0;
    auto alloc = [&](size_t bytes) {
        char* p = ws + off;
        off = (off + bytes + 511) & ~(size_t)511;
        return p;
    };
    float*  dinv   = (float*)alloc((size_t)N * 4);
    int*    pdeg   = (int*)alloc((size_t)N * 4);
    int*    rowptr = (int*)alloc((size_t)N * 4);
    int*    bktcur = (int*)alloc(128 * 4);
    int*    srcs   = (int*)alloc((size_t)128 * SCAP * 4);
    __half* xhP    = (__half*)alloc((size_t)(N + 1) * 128 * 2);
    __half* aggT   = (__half*)alloc((size_t)N * 128 * 2);
    __half* thP    = (__half*)alloc((size_t)(N + 1) * 64 * 2);
    unsigned* pairs = (unsigned*)thP;  // alias: dead until mgemm_fused

    // ---- CSR build: bin -> per-bucket build+scatter ----
    hipMemsetAsync(bktcur, 0, 128 * 4, stream);
    binA_k<<<(E + NT * KE - 1) / (NT * KE), NT, 0, stream>>>(
        srcp, dstp, bktcur, pairs, E);
    scatB_k<<<128, 1024, 0, stream>>>(pairs, bktcur, rowptr, pdeg, dinv, srcs, N);

    // ---- layer 1: xhP (dummy row zeroed) -> aggT ----
    conv1T_k<<<((N + 1) * 8 + NT - 1) / NT, NT, 0, stream>>>(x, dinv, xhP, N);
    gatherT128_k<<<((N + 31) / 32) * 8, NT, 0, stream>>>(
        rowptr, pdeg, srcs, dinv, xhP, (__half2*)aggT, N);

    // ---- fused MLP: aggT -> thP = (relu(aggT@W1+b1)@W2)*dinv ----
    mgemm_fused_k<<<(N + 63) / 64, NT, 0, stream>>>(
        aggT, W1, b1, W2, dinv, thP, N);

    // ---- layer 2 gather -> out (+b2) ----
    gatherT64_k<<<((N + 63) / 64) * 8, NT, 0, stream>>>(
        rowptr, pdeg, srcs, dinv, thP, b2, out, N);
}

// Round 21
// 198.300 us; speedup vs baseline: 1.5418x; 1.0116x over previous
//
#include <hip/hip_runtime.h>
#include <hip/hip_fp16.h>

// ---------------------------------------------------------------------------
// 2-layer GCN (PyG GCNConv): deg^{-1/2} sym norm with self-loops.
// Round 21 = round 20 + 16-edge gather batches (MLP doubling).
//   Evidence: gather128 at 0.15 req/cycle/CU, occupancy 75%, VALU 36% ->
//   in-flight-limited, not BW-limited. Pad edge lists to x16 and issue all
//   16 independent 64B loads per batch before accumulating (2 fdot2 chains,
//   2-register index prefetch) -> per-wave MLP doubles.
//   - scatB: pv = (c+15)&~15 (x16 padding), shfl-based scan (4 barriers).
//   - Rest = round 20: 2-kernel CSR build (binA fixed-stride buckets +
//     per-bucket scatB), paired-slice gathers (64B/request), fused MFMA MLP,
//     dummy index N -> zeroed payload row, fdot2 fp32 accumulation.
// ---------------------------------------------------------------------------

#define NT 256
#define KE 8            // edges per thread in binA
#define CAP 20480       // pairs capacity per bucket (actual ~12.5k)
#define SCAP 35872      // srcs slots per bucket (>= CAP + 15*1024 + 16)

typedef _Float16 half8 __attribute__((ext_vector_type(8)));
typedef _Float16 h2 __attribute__((ext_vector_type(2)));
typedef float floatx4 __attribute__((ext_vector_type(4)));

#if __has_builtin(__builtin_amdgcn_fdot2)
__device__ __forceinline__ float dot2f(h2 a, h2 b, float c) {
    return __builtin_amdgcn_fdot2(a, b, c, false);
}
#else
__device__ __forceinline__ float dot2f(h2 a, h2 b, float c) {
    return c + (float)a.x * (float)b.x + (float)a.y * (float)b.y;
}
#endif

// ---- phase A: bin edges into fixed-stride bucket regions ----
// pair word = (src << 10) | (dst & 1023); bucket = dst >> 10.
// bktcur[128] holds count cursors (pre-zeroed via memsetAsync).
__global__ __launch_bounds__(NT) void binA_k(
    const int* __restrict__ src, const int* __restrict__ dst,
    int* __restrict__ bktcur, unsigned* __restrict__ pairs, int e) {
    __shared__ int lh[128];
    __shared__ int lbase[128];
    int tid = threadIdx.x;
    if (tid < 128) lh[tid] = 0;
    __syncthreads();
    int base = blockIdx.x * (NT * KE);
    int sv[KE];
    unsigned meta[KE];
#pragma unroll
    for (int k = 0; k < KE; ++k) {
        int ei = base + k * NT + tid;
        if (ei < e) {
            int d = dst[ei];
            sv[k] = src[ei];
            int b = d >> 10;
            int lr = atomicAdd(&lh[b], 1);  // LDS atomic
            meta[k] = ((unsigned)b << 22) | ((unsigned)lr << 10) | (unsigned)(d & 1023);
        } else {
            sv[k] = 0;
            meta[k] = 0xffffffffu;
        }
    }
    __syncthreads();
    if (tid < 128 && lh[tid] > 0)
        lbase[tid] = atomicAdd(&bktcur[tid], lh[tid]);  // <=128 global/block
    __syncthreads();
#pragma unroll
    for (int k = 0; k < KE; ++k) {
        if (meta[k] != 0xffffffffu) {
            int b = (int)(meta[k] >> 22);
            int lr = (int)((meta[k] >> 10) & 0xfffu);
            pairs[(size_t)b * CAP + lbase[b] + lr] =
                ((unsigned)sv[k] << 10) | (meta[k] & 1023u);
        }
    }
}

// ---- phase B: per-bucket CSR build + scatter (1 block = 1 bucket) ----
// 1024 threads. Emits dinv, pdeg (x16-padded), rowptr (absolute,
// bucket-strided srcs), places srcs, fills pads (+16 tail slack).
__global__ __launch_bounds__(1024) void scatB_k(
    const unsigned* __restrict__ pairs, const int* __restrict__ bktcur,
    int* __restrict__ rowptr, int* __restrict__ pdeg, float* __restrict__ dinv,
    int* __restrict__ srcs, int n) {
    __shared__ int lc[1024];
    __shared__ int wpart[16], wpref[16];
    const int i = blockIdx.x;                 // 0..127
    const int b = (i & 7) * 16 + (i >> 3);    // bucket, XCD-local regions
    const int tid = threadIdx.x;
    const int nbase = b << 10;
    if (nbase >= n) return;
    const int cntb = bktcur[b];
    const size_t pbase = (size_t)b * CAP;
    const size_t sbase = (size_t)b * SCAP;

    lc[tid] = 0;
    __syncthreads();
    for (int j = tid; j < cntb; j += 1024)
        atomicAdd(&lc[pairs[pbase + j] & 1023u], 1);
    __syncthreads();

    const int c  = lc[tid];
    const int pv = (c + 15) & ~15;  // x16 padding for 16-edge gather batches

    // inclusive scan of pv: shfl within wave, serial over 16 wave partials
    int x = pv;
#pragma unroll
    for (int off = 1; off < 64; off <<= 1) {
        int t = __shfl_up(x, off, 64);
        if ((tid & 63) >= off) x += t;
    }
    if ((tid & 63) == 63) wpart[tid >> 6] = x;
    __syncthreads();
    if (tid < 16) {
        int s = 0;
        for (int j = 0; j <= tid; ++j) s += wpart[j];
        wpref[tid] = s;
    }
    __syncthreads();
    const int oex = x - pv + ((tid >= 64) ? wpref[(tid >> 6) - 1] : 0);
    const int total = wpref[15];

    const int d = nbase + tid;
    if (d < n) {
        rowptr[d] = (int)sbase + oex;
        pdeg[d]   = pv;
        dinv[d]   = rsqrtf((float)(c + 1));  // +1 self-loop
    }
    lc[tid] = oex;  // per-dst placement cursor
    __syncthreads();

    for (int j = tid; j < cntb; j += 1024) {
        unsigned p = pairs[pbase + j];
        int dl = (int)(p & 1023u);
        int pos = atomicAdd(&lc[dl], 1);
        srcs[sbase + pos] = (int)(p >> 10);
    }
    __syncthreads();

    // pads: [oex+c, oex+pv) per dst; +16 tail slack after bucket total
    for (int k = oex + c; k < oex + pv; ++k) srcs[sbase + k] = n;
    if (tid < 16) srcs[sbase + total + tid] = n;
}

// ---------------- conv1T: x -> xhP[4][N+1][32] fp16 (row N zeroed) ---------
__global__ void conv1T_k(const float* __restrict__ x, const float* __restrict__ dinv,
                         __half* __restrict__ xhP, int n) {
    int t = blockIdx.x * NT + threadIdx.x;
    int node = t >> 3;
    if (node > n) return;
    int q = t & 7;
    int4 o0, o1;
    if (node == n) {
        o0 = make_int4(0, 0, 0, 0);
        o1 = o0;
    } else {
        float dn = dinv[node];
        const float4* xp =
            reinterpret_cast<const float4*>(x + (size_t)node * 128 + q * 16);
        __half2 h[8];
#pragma unroll
        for (int j = 0; j < 4; ++j) {
            float4 a = xp[j];
            h[2 * j + 0] = __floats2half2_rn(a.x * dn, a.y * dn);
            h[2 * j + 1] = __floats2half2_rn(a.z * dn, a.w * dn);
        }
        o0 = reinterpret_cast<int4*>(h)[0];
        o1 = reinterpret_cast<int4*>(h)[1];
    }
    int4* op = reinterpret_cast<int4*>(
        xhP + ((size_t)(q >> 1) * (n + 1) + node) * 32 + (q & 1) * 16);
    op[0] = o0;
    op[1] = o1;
}

// ---------------- paired gathers: 16-lane groups, 16-edge batches ----------
// xhP/thP: [pair][N+1][32] fp16 -> 64 B per node per pair; row N zeros.
// Per 16-edge batch: 2 index loads (prefetched a batch ahead), 16 shfl
// broadcasts, 16 INDEPENDENT 64B loads issued before any accumulation,
// then 32 fdot2 over 2 chains. pdeg is x16 so no masks/ballots.

__global__ __launch_bounds__(NT) void gatherT128_k(
    const int* __restrict__ rowptr, const int* __restrict__ pdeg,
    const int* __restrict__ srcs, const float* __restrict__ dinv,
    const __half* __restrict__ xhP, __half2* __restrict__ aggT, int n) {
    const int q8    = blockIdx.x & 7;   // (pair, node-16-block parity)
    const int pair  = q8 & 3;
    const int chunk = blockIdx.x >> 3;
    const int lane  = threadIdx.x & 63;
    const int wid   = threadIdx.x >> 6;
    const int g     = lane >> 4;   // node sub-group 0..3
    const int c     = lane & 15;   // half2 col within 32-col pair
    const int node  = chunk * 32 + (q8 >> 2) * 16 + wid * 4 + g;
    if (node >= n) return;  // uniform within each 16-lane group

    const int e0 = rowptr[node];
    const int pd = pdeg[node];
    const char* base = (const char*)(xhP + (size_t)pair * (n + 1) * 32);
    const unsigned c4 = (unsigned)c * 4u;
    const int c7 = c & 7;
    const h2 b10 = {(_Float16)1.0f, (_Float16)0.0f};
    const h2 b01 = {(_Float16)0.0f, (_Float16)1.0f};

    // self-loop (64 B row)
    h2 fs = *(const h2*)(base + (size_t)node * 64 + c4);
    float ax0 = dot2f(fs, b10, 0.0f), ay0 = dot2f(fs, b01, 0.0f);
    float ax1 = 0.0f, ay1 = 0.0f;

    int sA = srcs[e0 + c7];
    int sB = srcs[e0 + 8 + c7];
    for (int jb = 0; jb < pd; jb += 16) {
        int nA = srcs[e0 + jb + 16 + c7];  // in-bounds: padded + 16 slack
        int nB = srcs[e0 + jb + 24 + c7];
        h2 f[16];
#pragma unroll
        for (int u = 0; u < 8; ++u) {
            int s = __shfl(sA, (lane & 0x30) | u, 64);
            f[u] = *(const h2*)(base + (unsigned)s * 64u + c4);
        }
#pragma unroll
        for (int u = 0; u < 8; ++u) {
            int s = __shfl(sB, (lane & 0x30) | u, 64);
            f[8 + u] = *(const h2*)(base + (unsigned)s * 64u + c4);
        }
#pragma unroll
        for (int u = 0; u < 8; ++u) {
            ax0 = dot2f(f[u], b10, ax0);
            ay0 = dot2f(f[u], b01, ay0);
            ax1 = dot2f(f[8 + u], b10, ax1);
            ay1 = dot2f(f[8 + u], b01, ay1);
        }
        sA = nA;
        sB = nB;
    }

    float dn = dinv[node];
    float ax = (ax0 + ax1) * dn, ay = (ay0 + ay1) * dn;
    int sl = pair * 2 + (c >> 3);  // aggT stays [8][N][16]
    aggT[((size_t)sl * n + node) * 8 + (c & 7)] = __floats2half2_rn(ax, ay);
}

// gatherT64: thP[2][N+1][32]; writes row-major fp32 out (+b2), 128B/group.
__global__ __launch_bounds__(NT) void gatherT64_k(
    const int* __restrict__ rowptr, const int* __restrict__ pdeg,
    const int* __restrict__ srcs, const float* __restrict__ dinv,
    const __half* __restrict__ thP, const float* __restrict__ b2,
    float* __restrict__ out, int n) {
    const int q8    = blockIdx.x & 7;
    const int pair  = q8 & 1;
    const int chunk = blockIdx.x >> 3;
    const int lane  = threadIdx.x & 63;
    const int wid   = threadIdx.x >> 6;
    const int g     = lane >> 4;
    const int c     = lane & 15;
    const int node  = chunk * 64 + (q8 >> 1) * 16 + wid * 4 + g;
    if (node >= n) return;

    const int e0 = rowptr[node];
    const int pd = pdeg[node];
    const char* base = (const char*)(thP + (size_t)pair * (n + 1) * 32);
    const unsigned c4 = (unsigned)c * 4u;
    const int c7 = c & 7;
    const h2 b10 = {(_Float16)1.0f, (_Float16)0.0f};
    const h2 b01 = {(_Float16)0.0f, (_Float16)1.0f};

    h2 fs = *(const h2*)(base + (size_t)node * 64 + c4);
    float ax0 = dot2f(fs, b10, 0.0f), ay0 = dot2f(fs, b01, 0.0f);
    float ax1 = 0.0f, ay1 = 0.0f;

    int sA = srcs[e0 + c7];
    int sB = srcs[e0 + 8 + c7];
    for (int jb = 0; jb < pd; jb += 16) {
        int nA = srcs[e0 + jb + 16 + c7];
        int nB = srcs[e0 + jb + 24 + c7];
        h2 f[16];
#pragma unroll
        for (int u = 0; u < 8; ++u) {
            int s = __shfl(sA, (lane & 0x30) | u, 64);
            f[u] = *(const h2*)(base + (unsigned)s * 64u + c4);
        }
#pragma unroll
        for (int u = 0; u < 8; ++u) {
            int s = __shfl(sB, (lane & 0x30) | u, 64);
            f[8 + u] = *(const h2*)(base + (unsigned)s * 64u + c4);
        }
#pragma unroll
        for (int u = 0; u < 8; ++u) {
            ax0 = dot2f(f[u], b10, ax0);
            ay0 = dot2f(f[u], b01, ay0);
            ax1 = dot2f(f[8 + u], b10, ax1);
            ay1 = dot2f(f[8 + u], b01, ay1);
        }
        sA = nA;
        sB = nB;
    }

    float dn = dinv[node];
    int col = pair * 32 + c * 2;
    *reinterpret_cast<float2*>(&out[(size_t)node * 64 + col]) =
        make_float2((ax0 + ax1) * dn + b2[col], (ay0 + ay1) * dn + b2[col + 1]);
}

// ---------------- fused MLP: thP = (relu(aggT@W1 + b1) @ W2) * dinv --------
__global__ __launch_bounds__(NT) void mgemm_fused_k(
    const __half* __restrict__ aggT, const float* __restrict__ W1,
    const float* __restrict__ b1, const float* __restrict__ W2,
    const float* __restrict__ dinv, __half* __restrict__ thP, int n) {
    __shared__ _Float16 h1s[64][136];

    const int wid  = threadIdx.x >> 6;
    const int lane = threadIdx.x & 63;
    const int lrow = lane & 15;
    const int kgrp = lane >> 4;

    if (blockIdx.x == 0 && threadIdx.x < 64) {
        int pr = threadIdx.x >> 5, j = threadIdx.x & 31;
        thP[((size_t)pr * (n + 1) + n) * 32 + j] = __float2half(0.0f);
    }

    half8 bf1[2][4];
    float bv[2];
#pragma unroll
    for (int nt = 0; nt < 2; ++nt) {
        int col = wid * 32 + nt * 16 + lrow;
#pragma unroll
        for (int kk = 0; kk < 4; ++kk)
#pragma unroll
            for (int j = 0; j < 8; ++j)
                bf1[nt][kk][j] = (_Float16)W1[(size_t)(kk * 32 + kgrp * 8 + j) * 128 + col];
        bv[nt] = b1[col];
    }
    half8 bf2[4];
    {
        int col = wid * 16 + lrow;
#pragma unroll
        for (int kk = 0; kk < 4; ++kk)
#pragma unroll
            for (int j = 0; j < 8; ++j)
                bf2[kk][j] = (_Float16)W2[(size_t)(kk * 32 + kgrp * 8 + j) * 64 + col];
    }

    const int m0 = blockIdx.x * 64;

    floatx4 acc1[4][2];
#pragma unroll
    for (int mt = 0; mt < 4; ++mt)
#pragma unroll
        for (int nt = 0; nt < 2; ++nt) acc1[mt][nt] = floatx4{0.f, 0.f, 0.f, 0.f};

#pragma unroll
    for (int kk = 0; kk < 4; ++kk) {
        const int k0 = kk * 32 + kgrp * 8;
        half8 af[4];
#pragma unroll
        for (int mt = 0; mt < 4; ++mt) {
            int row = m0 + mt * 16 + lrow;
            if (row >= n) row = n - 1;  // clamp; final stores guarded
            af[mt] = *reinterpret_cast<const half8*>(
                &aggT[(((size_t)(k0 >> 4)) * n + row) * 16 + (k0 & 15)]);
        }
#pragma unroll
        for (int mt = 0; mt < 4; ++mt)
#pragma unroll
            for (int nt = 0; nt < 2; ++nt)
                acc1[mt][nt] = __builtin_amdgcn_mfma_f32_16x16x32_f16(
                    af[mt], bf1[nt][kk], acc1[mt][nt], 0, 0, 0);
    }

#pragma unroll
    for (int mt = 0; mt < 4; ++mt) {
#pragma unroll
        for (int r = 0; r < 4; ++r) {
            int rloc = mt * 16 + kgrp * 4 + r;
#pragma unroll
            for (int nt = 0; nt < 2; ++nt) {
                float v = fmaxf(acc1[mt][nt][r] + bv[nt], 0.0f);
                h1s[rloc][wid * 32 + nt * 16 + lrow] = (_Float16)v;
            }
        }
    }
    __syncthreads();

    floatx4 acc2[4];
#pragma unroll
    for (int mt = 0; mt < 4; ++mt) acc2[mt] = floatx4{0.f, 0.f, 0.f, 0.f};

#pragma unroll
    for (int kk = 0; kk < 4; ++kk) {
        const int k0 = kk * 32 + kgrp * 8;
#pragma unroll
        for (int mt = 0; mt < 4; ++mt) {
            half8 af = *reinterpret_cast<const half8*>(&h1s[mt * 16 + lrow][k0]);
            acc2[mt] = __builtin_amdgcn_mfma_f32_16x16x32_f16(
                af, bf2[kk], acc2[mt], 0, 0, 0);
        }
    }

#pragma unroll
    for (int mt = 0; mt < 4; ++mt) {
#pragma unroll
        for (int r = 0; r < 4; ++r) {
            int row = m0 + mt * 16 + kgrp * 4 + r;
            if (row < n) {
                float v = acc2[mt][r] * dinv[row];
                int col = wid * 16 + lrow;
                thP[((size_t)(col >> 5) * (n + 1) + row) * 32 + (col & 31)] =
                    __float2half(v);
            }
        }
    }
}

// ---------------------------------------------------------------------------

extern "C" void kernel_launch(void* const* d_in, const int* in_sizes, int n_in,
                              void* d_out, int out_size, void* d_ws, size_t ws_size,
                              hipStream_t stream) {
    const float* x   = (const float*)d_in[0];
    const int*   ei  = (const int*)d_in[1];
    const float* W1  = (const float*)d_in[2];
    const float* b1  = (const float*)d_in[3];
    const float* W2  = (const float*)d_in[4];
    const float* b2  = (const float*)d_in[5];
    float*       out = (float*)d_out;

    const int N = in_sizes[0] / 128;
    const int E = in_sizes[1] / 2;
    const int* srcp = ei;      // edge_index[0]
    const int* dstp = ei + E;  // edge_index[1]

    // workspace (512B-aligned):
    //   dinv[N] | pdeg[N] | rowptr[N] | bktcur[128] | srcs[128*SCAP]
    //   | xhP[4][N+1][32] fp16 | aggT[8][N][16] fp16
    //   | thP[2][N+1][32] fp16  (pairs[128*CAP] u32 aliases thP: 10.5<12.8MB)
    char* ws = (char*)d_ws;
    size_t off = 0;
    auto alloc = [&](size_t bytes) {
        char* p = ws + off;
        off = (off + bytes + 511) & ~(size_t)511;
        return p;
    };
    float*  dinv   = (float*)alloc((size_t)N * 4);
    int*    pdeg   = (int*)alloc((size_t)N * 4);
    int*    rowptr = (int*)alloc((size_t)N * 4);
    int*    bktcur = (int*)alloc(128 * 4);
    int*    srcs   = (int*)alloc((size_t)128 * SCAP * 4);
    __half* xhP    = (__half*)alloc((size_t)(N + 1) * 128 * 2);
    __half* aggT   = (__half*)alloc((size_t)N * 128 * 2);
    __half* thP    = (__half*)alloc((size_t)(N + 1) * 64 * 2);
    unsigned* pairs = (unsigned*)thP;  // alias: dead until mgemm_fused

    // ---- CSR build: bin -> per-bucket build+scatter ----
    hipMemsetAsync(bktcur, 0, 128 * 4, stream);
    binA_k<<<(E + NT * KE - 1) / (NT * KE), NT, 0, stream>>>(
        srcp, dstp, bktcur, pairs, E);
    scatB_k<<<128, 1024, 0, stream>>>(pairs, bktcur, rowptr, pdeg, dinv, srcs, N);

    // ---- layer 1: xhP (dummy row zeroed) -> aggT ----
    conv1T_k<<<((N + 1) * 8 + NT - 1) / NT, NT, 0, stream>>>(x, dinv, xhP, N);
    gatherT128_k<<<((N + 31) / 32) * 8, NT, 0, stream>>>(
        rowptr, pdeg, srcs, dinv, xhP, (__half2*)aggT, N);

    // ---- fused MLP: aggT -> thP = (relu(aggT@W1+b1)@W2)*dinv ----
    mgemm_fused_k<<<(N + 63) / 64, NT, 0, stream>>>(
        aggT, W1, b1, W2, dinv, thP, N);

    // ---- layer 2 gather -> out (+b2) ----
    gatherT64_k<<<((N + 63) / 64) * 8, NT, 0, stream>>>(
        rowptr, pdeg, srcs, dinv, thP, b2, out, N);
}